// Round 3
// baseline (850.477 us; speedup 1.0000x reference)
//
#include <hip/hip_runtime.h>
#include <stdint.h>

#define N_NODES 100000
#define N_EDGES 1600000
#define FDIM 128
#define NH 8
#define NCLS 3

static constexpr float SCALE = 0.25f; // D^-0.5, D=16

// ---------------- histogram of dst ----------------
// edge_index staged by harness as int32: [2][E] flat; src = ei[e], dst = ei[E+e]
__global__ __launch_bounds__(256) void k_hist(const int* __restrict__ ei,
                                              int* __restrict__ cnt) {
    int e = blockIdx.x * 256 + threadIdx.x;
    if (e < N_EDGES) {
        int d = ei[N_EDGES + e];
        atomicAdd(&cnt[d], 1);
    }
}

// ---------------- scan step 1: block sums (1024 elems/block) ----------------
__global__ __launch_bounds__(256) void k_scan1(const int* __restrict__ cnt,
                                               int* __restrict__ bsum) {
    __shared__ int sd[256];
    int t = threadIdx.x;
    int i0 = blockIdx.x * 1024 + t * 4;
    int s = 0;
#pragma unroll
    for (int j = 0; j < 4; ++j) {
        int i = i0 + j;
        if (i < N_NODES) s += cnt[i];
    }
    sd[t] = s;
    __syncthreads();
    for (int off = 128; off > 0; off >>= 1) {
        if (t < off) sd[t] += sd[t + off];
        __syncthreads();
    }
    if (t == 0) bsum[blockIdx.x] = sd[0];
}

// ---------------- scan step 2: scan of 98 block sums ----------------
__global__ __launch_bounds__(128) void k_scan2(const int* __restrict__ bsum,
                                               int* __restrict__ boff,
                                               int* __restrict__ row_start) {
    __shared__ int sd[128];
    int t = threadIdx.x;
    int v = (t < 98) ? bsum[t] : 0;
    sd[t] = v;
    __syncthreads();
    for (int off = 1; off < 128; off <<= 1) {
        int add = (t >= off) ? sd[t - off] : 0;
        __syncthreads();
        sd[t] += add;
        __syncthreads();
    }
    if (t < 98) boff[t] = sd[t] - v; // exclusive
    if (t == 0) row_start[N_NODES] = N_EDGES;
}

// ---------------- scan step 3: full exclusive scan -> row_start, cursor ----------------
__global__ __launch_bounds__(256) void k_scan3(const int* __restrict__ cnt,
                                               const int* __restrict__ boff,
                                               int* __restrict__ row_start,
                                               int* __restrict__ cursor) {
    __shared__ int sd[256];
    int t = threadIdx.x;
    int i0 = blockIdx.x * 1024 + t * 4;
    int c[4];
    int s = 0;
#pragma unroll
    for (int j = 0; j < 4; ++j) {
        int i = i0 + j;
        c[j] = (i < N_NODES) ? cnt[i] : 0;
        s += c[j];
    }
    sd[t] = s;
    __syncthreads();
    for (int off = 1; off < 256; off <<= 1) {
        int add = (t >= off) ? sd[t - off] : 0;
        __syncthreads();
        sd[t] += add;
        __syncthreads();
    }
    int run = boff[blockIdx.x] + sd[t] - s;
#pragma unroll
    for (int j = 0; j < 4; ++j) {
        int i = i0 + j;
        if (i < N_NODES) { row_start[i] = run; cursor[i] = run; }
        run += c[j];
    }
}

// ---------------- scatter edges into CSR order, folding edge_attr into record ----------------
// se4 = { src_as_float_bits, ea0, ea1, unused }
__global__ __launch_bounds__(256) void k_scatter(const int* __restrict__ ei,
                                                 const float* __restrict__ ea,
                                                 int* __restrict__ cursor,
                                                 float4* __restrict__ se4) {
    int e = blockIdx.x * 256 + threadIdx.x;
    if (e < N_EDGES) {
        int s = ei[e];
        int d = ei[N_EDGES + e];
        float2 a = *(const float2*)(ea + (long)e * 2);
        int pos = atomicAdd(&cursor[d], 1);
        se4[pos] = make_float4(__int_as_float(s), a.x, a.y, 0.0f);
    }
}

// ---------------- tiled fp32 GEMM: C[N x COLS] = A[N x 128] @ W[128 x COLS] ----------------
// optional epilogue: + bias + residual  (RESID=true)
template <int COLS, bool RESID>
__global__ __launch_bounds__(256) void k_gemm(const float* __restrict__ A,
                                              const float* __restrict__ W,
                                              const float* __restrict__ bias,
                                              const float* __restrict__ resid,
                                              float* __restrict__ C) {
    __shared__ float xT[128 * 68]; // [k][row], padded stride 68
    int rb = blockIdx.x * 64;
    int cb = blockIdx.y * 64;
    int t = threadIdx.x;
    int tx = t & 15, ty = t >> 4;

    // stage A rows rb..rb+63 transposed into LDS
#pragma unroll
    for (int it = 0; it < 8; ++it) {
        int f = (it * 256 + t) * 4;
        int r = f >> 7;
        int kk = f & 127;
        int row = rb + r;
        float4 v = make_float4(0.f, 0.f, 0.f, 0.f);
        if (row < N_NODES) v = *(const float4*)(A + (long)row * 128 + kk);
        xT[(kk + 0) * 68 + r] = v.x;
        xT[(kk + 1) * 68 + r] = v.y;
        xT[(kk + 2) * 68 + r] = v.z;
        xT[(kk + 3) * 68 + r] = v.w;
    }
    __syncthreads();

    float acc[4][4] = {};
    const float* Wp = W + cb + tx * 4;
#pragma unroll 8
    for (int k = 0; k < 128; ++k) {
        float4 xv = *(const float4*)(xT + k * 68 + ty * 4);
        float4 wv = *(const float4*)(Wp + (long)k * COLS);
        acc[0][0] += xv.x * wv.x; acc[0][1] += xv.x * wv.y; acc[0][2] += xv.x * wv.z; acc[0][3] += xv.x * wv.w;
        acc[1][0] += xv.y * wv.x; acc[1][1] += xv.y * wv.y; acc[1][2] += xv.y * wv.z; acc[1][3] += xv.y * wv.w;
        acc[2][0] += xv.z * wv.x; acc[2][1] += xv.z * wv.y; acc[2][2] += xv.z * wv.z; acc[2][3] += xv.z * wv.w;
        acc[3][0] += xv.w * wv.x; acc[3][1] += xv.w * wv.y; acc[3][2] += xv.w * wv.z; acc[3][3] += xv.w * wv.w;
    }

    float4 bv = make_float4(0.f, 0.f, 0.f, 0.f);
    if (RESID) bv = *(const float4*)(bias + cb + tx * 4);
#pragma unroll
    for (int i = 0; i < 4; ++i) {
        int row = rb + ty * 4 + i;
        if (row < N_NODES) {
            float4 o = make_float4(acc[i][0], acc[i][1], acc[i][2], acc[i][3]);
            if (RESID) {
                float4 rv = *(const float4*)(resid + (long)row * 128 + cb + tx * 4);
                o.x += rv.x + bv.x; o.y += rv.y + bv.y;
                o.z += rv.z + bv.z; o.w += rv.w + bv.w;
            }
            *(float4*)(C + (long)row * COLS + cb + tx * 4) = o;
        }
    }
}

// ---------------- per-node edge attention (one wave per node, 2-edge unrolled) ----------------
__global__ __launch_bounds__(256) void k_attn(const float* __restrict__ qkv,
                                              const float4* __restrict__ se4,
                                              const int* __restrict__ row_start,
                                              const float* __restrict__ Wedge,
                                              float* __restrict__ agg) {
    int wave = threadIdx.x >> 6;
    int lane = threadIdx.x & 63;
    int node = blockIdx.x * 4 + wave;
    if (node >= N_NODES) return;
    int h = lane >> 3; // head of this lane's 2 dims (flat f = 2*lane, head = f/16)
    float we0 = Wedge[h];
    float we1 = Wedge[8 + h];
    float2 q = *(const float2*)(qkv + (long)node * 384 + lane * 2);
    int p0 = row_start[node], p1 = row_start[node + 1];

    float accAx = 0.f, accAy = 0.f, denA = 0.f;
    float accBx = 0.f, accBy = 0.f, denB = 0.f;

    int p = p0;
    for (; p + 2 <= p1; p += 2) {
        float4 eA = se4[p];
        float4 eB = se4[p + 1];
        const float* kA = qkv + (long)__float_as_int(eA.x) * 384 + 128 + lane * 2;
        const float* kB = qkv + (long)__float_as_int(eB.x) * 384 + 128 + lane * 2;
        float2 kkA = *(const float2*)(kA);
        float2 kkB = *(const float2*)(kB);
        float2 vvA = *(const float2*)(kA + 128);
        float2 vvB = *(const float2*)(kB + 128);
        float pa = q.x * kkA.x + q.y * kkA.y;
        float pb = q.x * kkB.x + q.y * kkB.y;
        pa += __shfl_xor(pa, 1);  pb += __shfl_xor(pb, 1);
        pa += __shfl_xor(pa, 2);  pb += __shfl_xor(pb, 2);
        pa += __shfl_xor(pa, 4);  pb += __shfl_xor(pb, 4);
        float sa = pa * SCALE + eA.y * we0 + eA.z * we1;
        float sb = pb * SCALE + eB.y * we0 + eB.z * we1;
        float wa = __expf(sa);
        float wb = __expf(sb);
        denA += wa;             denB += wb;
        accAx += wa * vvA.x;    accBx += wb * vvB.x;
        accAy += wa * vvA.y;    accBy += wb * vvB.y;
    }
    if (p < p1) {
        float4 eA = se4[p];
        const float* kA = qkv + (long)__float_as_int(eA.x) * 384 + 128 + lane * 2;
        float2 kkA = *(const float2*)(kA);
        float2 vvA = *(const float2*)(kA + 128);
        float pa = q.x * kkA.x + q.y * kkA.y;
        pa += __shfl_xor(pa, 1);
        pa += __shfl_xor(pa, 2);
        pa += __shfl_xor(pa, 4);
        float sa = pa * SCALE + eA.y * we0 + eA.z * we1;
        float wa = __expf(sa);
        denA += wa;
        accAx += wa * vvA.x;
        accAy += wa * vvA.y;
    }
    float den = denA + denB;
    float inv = 1.0f / (den + 1e-16f);
    float ox = (accAx + accBx) * inv;
    float oy = (accAy + accBy) * inv;
    *(float2*)(agg + (long)node * 128 + lane * 2) = make_float2(ox, oy);
}

// ---------------- LN + MLP (fused), 4 nodes per wave ----------------
__global__ __launch_bounds__(256) void k_mlp(const float* __restrict__ h_pre,
                                             const float* __restrict__ ln_w,
                                             const float* __restrict__ ln_b,
                                             const float* __restrict__ Wc1,
                                             const float* __restrict__ bc1,
                                             const float* __restrict__ Wc2,
                                             const float* __restrict__ bc2,
                                             float* __restrict__ out) {
    __shared__ float sW1[128 * 64];
    __shared__ float sW2[64 * 3];
    __shared__ float sb1[64];
    __shared__ float sb2[3];
    __shared__ float hbuf[4][4][128];
    int t = threadIdx.x;
#pragma unroll
    for (int it = 0; it < 8; ++it) {
        int f = (it * 256 + t) * 4;
        *(float4*)(sW1 + f) = *(const float4*)(Wc1 + f);
    }
    if (t < 192) sW2[t] = Wc2[t];
    if (t < 64) sb1[t] = bc1[t];
    if (t < 3) sb2[t] = bc2[t];
    __syncthreads();

    int wave = t >> 6, lane = t & 63;
    float2 lw = *(const float2*)(ln_w + lane * 2);
    float2 lb = *(const float2*)(ln_b + lane * 2);
    int nb0 = (blockIdx.x * 4 + wave) * 4;

#pragma unroll
    for (int nb = 0; nb < 4; ++nb) {
        int node = nb0 + nb;
        float2 hv = *(const float2*)(h_pre + (long)node * 128 + lane * 2);
        float s = hv.x + hv.y;
#pragma unroll
        for (int off = 32; off > 0; off >>= 1) s += __shfl_xor(s, off);
        float mu = s * (1.0f / 128.0f);
        float dx = hv.x - mu, dy = hv.y - mu;
        float s2 = dx * dx + dy * dy;
#pragma unroll
        for (int off = 32; off > 0; off >>= 1) s2 += __shfl_xor(s2, off);
        float rstd = rsqrtf(s2 * (1.0f / 128.0f) + 1e-5f);
        hbuf[wave][nb][lane * 2] = dx * rstd * lw.x + lb.x;
        hbuf[wave][nb][lane * 2 + 1] = dy * rstd * lw.y + lb.y;
    }
    __syncthreads();

    float acc[4];
#pragma unroll
    for (int nb = 0; nb < 4; ++nb) acc[nb] = sb1[lane];
#pragma unroll 4
    for (int c = 0; c < 128; ++c) {
        float w = sW1[c * 64 + lane];
        acc[0] += hbuf[wave][0][c] * w;
        acc[1] += hbuf[wave][1][c] * w;
        acc[2] += hbuf[wave][2][c] * w;
        acc[3] += hbuf[wave][3][c] * w;
    }
#pragma unroll
    for (int nb = 0; nb < 4; ++nb) {
        float a = fmaxf(acc[nb], 0.f);
#pragma unroll
        for (int c2 = 0; c2 < NCLS; ++c2) {
            float pv = a * sW2[lane * 3 + c2];
#pragma unroll
            for (int off = 32; off > 0; off >>= 1) pv += __shfl_xor(pv, off);
            if (lane == 0) out[(long)(nb0 + nb) * 3 + c2] = pv + sb2[c2];
        }
    }
}

extern "C" void kernel_launch(void* const* d_in, const int* in_sizes, int n_in,
                              void* d_out, int out_size, void* d_ws, size_t ws_size,
                              hipStream_t stream) {
    const float* x         = (const float*)d_in[0];
    const int*   edge_index= (const int*)d_in[1];   // harness stages integers as int32
    const float* edge_attr = (const float*)d_in[2];
    const float* Wqkv      = (const float*)d_in[3];
    const float* Wedge     = (const float*)d_in[4];
    const float* Wout      = (const float*)d_in[5];
    const float* bout      = (const float*)d_in[6];
    const float* ln_w      = (const float*)d_in[7];
    const float* ln_b      = (const float*)d_in[8];
    const float* Wc1       = (const float*)d_in[9];
    const float* bc1       = (const float*)d_in[10];
    const float* Wc2       = (const float*)d_in[11];
    const float* bc2       = (const float*)d_in[12];
    float* out = (float*)d_out;

    // workspace layout (~232 MB; h_pre aliases qkv, which is dead after k_attn)
    char* ws = (char*)d_ws;
    size_t o = 0;
    auto alloc = [&](size_t bytes) -> char* {
        char* p = ws + o;
        o = (o + bytes + 255) & ~(size_t)255;
        return p;
    };
    int*    cnt       = (int*)alloc((size_t)N_NODES * 4);
    int*    row_start = (int*)alloc((size_t)(N_NODES + 1) * 4);
    int*    cursor    = (int*)alloc((size_t)N_NODES * 4);
    int*    bsum      = (int*)alloc(98 * 4);
    int*    boff      = (int*)alloc(98 * 4);
    float4* se4       = (float4*)alloc((size_t)N_EDGES * 16);
    float*  agg       = (float*)alloc((size_t)N_NODES * 128 * 4);
    float*  qkv       = (float*)alloc((size_t)N_NODES * 384 * 4);
    float*  h_pre     = qkv; // alias: qkv dead once k_attn completes
    (void)ws_size; (void)in_sizes; (void)n_in; (void)out_size;

    hipMemsetAsync(cnt, 0, (size_t)N_NODES * 4, stream);
    k_hist<<<N_EDGES / 256, 256, 0, stream>>>(edge_index, cnt);
    k_scan1<<<98, 256, 0, stream>>>(cnt, bsum);
    k_scan2<<<1, 128, 0, stream>>>(bsum, boff, row_start);
    k_scan3<<<98, 256, 0, stream>>>(cnt, boff, row_start, cursor);
    k_scatter<<<N_EDGES / 256, 256, 0, stream>>>(edge_index, edge_attr, cursor, se4);

    k_gemm<384, false><<<dim3(1563, 6), 256, 0, stream>>>(x, Wqkv, nullptr, nullptr, qkv);
    k_attn<<<25000, 256, 0, stream>>>(qkv, se4, row_start, Wedge, agg);
    k_gemm<128, true><<<dim3(1563, 2), 256, 0, stream>>>(agg, Wout, bout, x, h_pre);
    k_mlp<<<6250, 256, 0, stream>>>(h_pre, ln_w, ln_b, Wc1, bc1, Wc2, bc2, out);
}